// Round 3
// baseline (103.985 us; speedup 1.0000x reference)
//
#include <hip/hip_runtime.h>
#include <hip/hip_bf16.h>

typedef __bf16 bf16x8 __attribute__((ext_vector_type(8)));
typedef float  f32x4  __attribute__((ext_vector_type(4)));

constexpr int kD  = 512;
constexpr int kBD = 64;
constexpr int kN  = 4096;
constexpr int kB  = 8;

constexpr int ROWS = 16;    // MFMA M
constexpr int CPB  = 4;     // chunks per block -> 64 rows/block -> grid 512
constexpr int STEPS = CPB * 16;   // 64 fully-unrolled K-steps

__device__ __forceinline__ bf16x8 cvt8(float4 a, float4 b) {
    bf16x8 r;
    r[0] = (__bf16)a.x; r[1] = (__bf16)a.y; r[2] = (__bf16)a.z; r[3] = (__bf16)a.w;
    r[4] = (__bf16)b.x; r[5] = (__bf16)b.y; r[6] = (__bf16)b.z; r[7] = (__bf16)b.w;
    return r;
}

// S[b,j] = sum_n (keys[b,n,:].Wbk[j,:] + bbk[j]) * (values[b,n,:].Wbv[j,:] + bbv[j])
//
// No LDS, no barriers: each wave owns one 16-j tile (weights in 128 VGPRs) and
// streams 64 rows; A-fragments load global->reg through a 4-slot pipeline, so
// the compiler emits counted vmcnt(N) and ~16KB/wave stays in flight.
__global__ __launch_bounds__(256, 2)
void lbm_bind(const float* __restrict__ keys, const float* __restrict__ values,
              const float* __restrict__ Wbk,  const float* __restrict__ bbk,
              const float* __restrict__ Wbv,  const float* __restrict__ bbv,
              float* __restrict__ S)
{
    const int tid = threadIdx.x;
    const int wv  = tid >> 6;
    const int ln  = tid & 63;
    const int l15 = ln & 15;
    const int lhi = ln >> 4;
    const int jrow = wv * 16 + l15;     // weight row (j) for B-operand
    const int dk   = lhi * 8;

    const int blockRow0 = blockIdx.x * (ROWS * CPB);

    // ---- weight B-fragments -> registers (bf16), once per block ----
    bf16x8 wk[16], wvv[16];
    #pragma unroll
    for (int d0 = 0; d0 < 16; ++d0) {
        const float* pk = Wbk + jrow * kD + d0 * 32 + dk;
        const float* pv = Wbv + jrow * kD + d0 * 32 + dk;
        wk[d0]  = cvt8(*(const float4*)pk, *(const float4*)(pk + 4));
        wvv[d0] = cvt8(*(const float4*)pv, *(const float4*)(pv + 4));
    }
    const float bk = bbk[jrow];
    const float bv = bbv[jrow];

    // per-lane stream base: row = blockRow0 + l15, k-offset = lhi*8
    const float* kp = keys   + (size_t)(blockRow0 + l15) * kD + dk;
    const float* vp = values + (size_t)(blockRow0 + l15) * kD + dk;

    // step s: chunk c = s>>4 (row += 16c), d-step d0 = s&15
    float4 ska[4], skb[4], sva[4], svb[4];   // 4-slot prefetch pipeline

#define LDSTEP(s, slot)                                                     \
    {                                                                       \
        const int off_ = ((s) >> 4) * (ROWS * kD) + ((s) & 15) * 32;        \
        ska[slot] = *(const float4*)(kp + off_);                            \
        skb[slot] = *(const float4*)(kp + off_ + 4);                        \
        sva[slot] = *(const float4*)(vp + off_);                            \
        svb[slot] = *(const float4*)(vp + off_ + 4);                        \
    }

    LDSTEP(0, 0) LDSTEP(1, 1) LDSTEP(2, 2) LDSTEP(3, 3)

    float sreg = 0.0f;
    f32x4 kacc = {0.f, 0.f, 0.f, 0.f};
    f32x4 vacc = {0.f, 0.f, 0.f, 0.f};

    #pragma unroll
    for (int s = 0; s < STEPS; ++s) {
        const int slot = s & 3;
        const int d0   = s & 15;
        kacc = __builtin_amdgcn_mfma_f32_16x16x32_bf16(cvt8(ska[slot], skb[slot]), wk[d0],  kacc, 0, 0, 0);
        vacc = __builtin_amdgcn_mfma_f32_16x16x32_bf16(cvt8(sva[slot], svb[slot]), wvv[d0], vacc, 0, 0, 0);
        if (s + 4 < STEPS) LDSTEP(s + 4, slot)
        if (d0 == 15) {     // end of a 16-row chunk: combine K/V projections
            #pragma unroll
            for (int i = 0; i < 4; ++i)
                sreg += (kacc[i] + bk) * (vacc[i] + bv);
            #pragma unroll
            for (int i = 0; i < 4; ++i) { kacc[i] = 0.f; vacc[i] = 0.f; }
        }
    }
#undef LDSTEP

    // reduce over the 4 row-groups (C/D rows live in lanes ^16, ^32)
    sreg += __shfl_xor(sreg, 16);
    sreg += __shfl_xor(sreg, 32);
    if (lhi == 0) {
        int b = blockRow0 / kN;
        atomicAdd(&S[b * kBD + jrow], sreg);
    }
}

// Fused tail: 64 blocks; each block redundantly computes S->Bsum->ms->ext->LN
// for its batch b (tiny), then produces its 64-wide slice of out = normed.Wo^T + bo.
__global__ __launch_bounds__(256)
void lbm_tail(const float* __restrict__ S,    const float* __restrict__ query,
              const float* __restrict__ Wbc,  const float* __restrict__ bbc,
              const float* __restrict__ Wuq,  const float* __restrict__ buq,
              const float* __restrict__ Wue,  const float* __restrict__ bue,
              const float* __restrict__ ln_g, const float* __restrict__ ln_b,
              const float* __restrict__ Wo,   const float* __restrict__ bo,
              float* __restrict__ out)
{
    const int b = blockIdx.x >> 3;
    const int s = blockIdx.x & 7;          // 64-wide output slice
    const int t = threadIdx.x;

    __shared__ float shS[kBD];
    __shared__ float shB[kD];
    __shared__ float shMs[kBD];
    __shared__ float shN[kD];
    __shared__ float redT[4][kBD];
    __shared__ float redQ[4][kBD];
    __shared__ float redLN[8];
    __shared__ float s_mu, s_rs;

    if (t < kBD) shS[t] = S[b * kBD + t];
    __syncthreads();

    // Bsum[d] = sum_j S[j]*Wbc[d,j] + n*bbc[d]
    for (int d = t; d < kD; d += 256) {
        const float4* wr = (const float4*)(Wbc + d * kBD);
        float acc = 0.f;
        #pragma unroll
        for (int q4 = 0; q4 < 16; ++q4) {
            float4 w = wr[q4];
            acc += w.x * shS[q4*4+0] + w.y * shS[q4*4+1]
                 + w.z * shS[q4*4+2] + w.w * shS[q4*4+3];
        }
        shB[d] = acc + (float)kN * bbc[d];
    }
    __syncthreads();

    // t[jj] = Bsum.Wuq[jj,:] + n*buq ; q[jj] = query.Wuq[jj,:] + buq ; ms = q*t
    {
        const int jj = t & 63, qq = t >> 6;
        const float4* wr = (const float4*)(Wuq + jj * kD + qq * 128);
        const float4* qr = (const float4*)(query + b * kD + qq * 128);
        const float4* br = (const float4*)(shB + qq * 128);
        float at = 0.f, aq = 0.f;
        #pragma unroll
        for (int i = 0; i < 32; ++i) {
            float4 w = wr[i]; float4 bb = br[i]; float4 qv = qr[i];
            at += w.x*bb.x + w.y*bb.y + w.z*bb.z + w.w*bb.w;
            aq += w.x*qv.x + w.y*qv.y + w.z*qv.z + w.w*qv.w;
        }
        redT[qq][jj] = at; redQ[qq][jj] = aq;
    }
    __syncthreads();
    if (t < kBD) {
        float tv = redT[0][t] + redT[1][t] + redT[2][t] + redT[3][t] + (float)kN * buq[t];
        float qv = redQ[0][t] + redQ[1][t] + redQ[2][t] + redQ[3][t] + buq[t];
        shMs[t] = tv * qv;
    }
    __syncthreads();

    // ext[d] -> ret -> LN stats
    float lsum = 0.f, lsq = 0.f;
    for (int d = t; d < kD; d += 256) {
        const float4* wr = (const float4*)(Wue + d * kBD);
        float acc = 0.f;
        #pragma unroll
        for (int q4 = 0; q4 < 16; ++q4) {
            float4 w = wr[q4];
            acc += w.x * shMs[q4*4+0] + w.y * shMs[q4*4+1]
                 + w.z * shMs[q4*4+2] + w.w * shMs[q4*4+3];
        }
        float ret = (acc + (float)kN * bue[d]) * (1.0f / 64.0f);
        shN[d] = ret;
        lsum += ret; lsq += ret * ret;
    }
    #pragma unroll
    for (int m = 1; m < 64; m <<= 1) {
        lsum += __shfl_xor(lsum, m);
        lsq  += __shfl_xor(lsq, m);
    }
    if ((t & 63) == 0) { redLN[t >> 6] = lsum; redLN[4 + (t >> 6)] = lsq; }
    __syncthreads();
    if (t == 0) {
        float s0 = redLN[0] + redLN[1] + redLN[2] + redLN[3];
        float s1 = redLN[4] + redLN[5] + redLN[6] + redLN[7];
        float mu = s0 / (float)kD;
        float var = s1 / (float)kD - mu * mu;
        s_mu = mu;
        s_rs = rsqrtf(var + 1e-5f);
    }
    __syncthreads();
    {
        float mu = s_mu, rs = s_rs;
        for (int d = t; d < kD; d += 256)
            shN[d] = (shN[d] - mu) * rs * ln_g[d] + ln_b[d];
    }
    __syncthreads();

    // out slice: d = s*64 + t/4, quarter q = t&3 over the 512-dot
    {
        const int d = s * 64 + (t >> 2);
        const int q = t & 3;
        const float4* wr = (const float4*)(Wo + d * kD + q * 128);
        const float4* nr = (const float4*)(shN + q * 128);
        float acc = 0.f;
        #pragma unroll
        for (int i = 0; i < 32; ++i) {
            float4 w = wr[i]; float4 nv = nr[i];
            acc += w.x*nv.x + w.y*nv.y + w.z*nv.z + w.w*nv.w;
        }
        acc += __shfl_xor(acc, 1);
        acc += __shfl_xor(acc, 2);
        if (q == 0) out[b * kD + d] = acc + bo[d];
    }
}

extern "C" void kernel_launch(void* const* d_in, const int* in_sizes, int n_in,
                              void* d_out, int out_size, void* d_ws, size_t ws_size,
                              hipStream_t stream) {
    const float* keys   = (const float*)d_in[0];
    const float* values = (const float*)d_in[1];
    const float* query  = (const float*)d_in[2];
    const float* Wbk    = (const float*)d_in[3];
    const float* bbk    = (const float*)d_in[4];
    const float* Wbv    = (const float*)d_in[5];
    const float* bbv    = (const float*)d_in[6];
    const float* Wbc    = (const float*)d_in[7];
    const float* bbc    = (const float*)d_in[8];
    const float* Wuq    = (const float*)d_in[9];
    const float* buq    = (const float*)d_in[10];
    const float* Wue    = (const float*)d_in[11];
    const float* bue    = (const float*)d_in[12];
    const float* ln_g   = (const float*)d_in[13];
    const float* ln_b   = (const float*)d_in[14];
    const float* Wo     = (const float*)d_in[15];
    const float* bo     = (const float*)d_in[16];

    float* S   = (float*)d_ws;      // [8][64] accumulator
    float* out = (float*)d_out;

    hipMemsetAsync(S, 0, kB * kBD * sizeof(float), stream);

    const int nblocks = (kB * kN) / (ROWS * CPB);   // 512
    lbm_bind<<<dim3(nblocks), dim3(256), 0, stream>>>(keys, values, Wbk, bbk, Wbv, bbv, S);
    lbm_tail<<<dim3(kB * 8), dim3(256), 0, stream>>>(S, query, Wbc, bbc, Wuq, buq,
                                                     Wue, bue, ln_g, ln_b, Wo, bo, out);
}

// Round 4
// 63.190 us; speedup vs baseline: 1.6456x; 1.6456x over previous
//
#include <hip/hip_runtime.h>
#include <hip/hip_bf16.h>

typedef __bf16 bf16x8 __attribute__((ext_vector_type(8)));
typedef float  f32x4  __attribute__((ext_vector_type(4)));

constexpr int kD  = 512;
constexpr int kBD = 64;
constexpr int kN  = 4096;
constexpr int kB  = 8;

constexpr int ROWS  = 16;            // MFMA M
constexpr int CPB   = 4;             // chunks per block -> 64 rows/block -> grid 512
constexpr int NPH   = CPB * 4;       // 16 phases; phase = 16 rows x 128 d (8 KB/array)
constexpr int SLOTS = 5;             // 5-deep slot ring: prefetch target = slot retired last phase
constexpr int UNITF = ROWS * 128;    // floats per unit (2048 = 8 KB)

typedef const __attribute__((address_space(1))) void* gas_t;
typedef __attribute__((address_space(3))) void*       las_t;

static __device__ __forceinline__ void gload16(const void* g, void* l) {
    __builtin_amdgcn_global_load_lds((gas_t)g, (las_t)l, 16, 0, 0);
}

__device__ __forceinline__ bf16x8 cvt8(float4 a, float4 b) {
    bf16x8 r;
    r[0] = (__bf16)a.x; r[1] = (__bf16)a.y; r[2] = (__bf16)a.z; r[3] = (__bf16)a.w;
    r[4] = (__bf16)b.x; r[5] = (__bf16)b.y; r[6] = (__bf16)b.z; r[7] = (__bf16)b.w;
    return r;
}

// S[b,j] = sum_n (keys[b,n,:].Wbk[j,:] + bbk[j]) * (values[b,n,:].Wbv[j,:] + bbv[j])
//
// T3+T4 pipeline: 16 quarter-chunk phases; counted vmcnt(12) + raw s_barrier keeps
// 3 phases (48 KB/block) of global_load_lds in flight at all times -- never drains.
// LDS: 5-slot ring per array, linear layout; source 16B granules XOR-pre-swizzled
// (g' = g ^ (row&7)) so fragment ds_read_b128 is 2-way-aliased (free) not 16-way.
__global__ __launch_bounds__(256, 2)
void lbm_bind(const float* __restrict__ keys, const float* __restrict__ values,
              const float* __restrict__ Wbk,  const float* __restrict__ bbk,
              const float* __restrict__ Wbv,  const float* __restrict__ bbv,
              float* __restrict__ S)
{
    __shared__ float ldsK[SLOTS * UNITF];
    __shared__ float ldsV[SLOTS * UNITF];

    const int tid = threadIdx.x;
    const int wv  = tid >> 6;
    const int ln  = tid & 63;
    const int l15 = ln & 15;
    const int lhi = ln >> 4;
    const int sw  = l15 & 7;            // row XOR swizzle key
    const int jrow = wv * 16 + l15;     // weight row (j) for B-operand
    const int dk   = lhi * 8;

    const int blockRow0 = blockIdx.x * (ROWS * CPB);

    // STAGE phase p: chunk c=p>>2, quarter q=p&3, slot p%5. 4 gload_lds per thread.
#define STAGE(p)                                                              \
    {                                                                         \
        const int c_ = (p) >> 2, q_ = (p) & 3, sl_ = (p) % SLOTS;             \
        _Pragma("unroll")                                                     \
        for (int i_ = 0; i_ < 2; ++i_) {                                      \
            int g_  = i_ * 256 + tid;        /* granule 0..511 */             \
            int r_  = g_ >> 5;               /* row 0..15 */                  \
            int gl_ = g_ & 31;               /* LDS granule in row-quarter */ \
            int gs_ = gl_ ^ (r_ & 7);        /* source granule */             \
            size_t so_ = (size_t)(blockRow0 + c_ * ROWS + r_) * kD + q_ * 128 + gs_ * 4; \
            gload16(keys   + so_, &ldsK[sl_ * UNITF + g_ * 4]);               \
            gload16(values + so_, &ldsV[sl_ * UNITF + g_ * 4]);               \
        }                                                                     \
    }

    // prologue: 4 phases in flight before anything else
    STAGE(0) STAGE(1) STAGE(2) STAGE(3)

    // ---- weight B-fragments -> registers (bf16 in f32x4 carriers), once per block ----
    f32x4 wk[16], wvv[16];
    #pragma unroll
    for (int d0 = 0; d0 < 16; ++d0) {
        const float* pk = Wbk + jrow * kD + d0 * 32 + dk;
        const float* pv = Wbv + jrow * kD + d0 * 32 + dk;
        wk[d0]  = __builtin_bit_cast(f32x4, cvt8(*(const float4*)pk, *(const float4*)(pk + 4)));
        wvv[d0] = __builtin_bit_cast(f32x4, cvt8(*(const float4*)pv, *(const float4*)(pv + 4)));
    }
    // pin: forbid rematerialization/sinking of the weight regs (round-3 collapse)
    #pragma unroll
    for (int d0 = 0; d0 < 16; ++d0) {
        asm volatile("" : "+v"(wk[d0]));
        asm volatile("" : "+v"(wvv[d0]));
    }
    const float bk = bbk[jrow];
    const float bv = bbv[jrow];

    float sreg = 0.0f;
    f32x4 kacc = {0.f, 0.f, 0.f, 0.f};
    f32x4 vacc = {0.f, 0.f, 0.f, 0.f};

    for (int c = 0; c < CPB; ++c) {          // rolled: weight indices stay static below
        #pragma unroll
        for (int q = 0; q < 4; ++q) {
            const int p = c * 4 + q;
            // counted wait: 3 younger phases (12 instr) stay in flight
            asm volatile("s_waitcnt vmcnt(12)" ::: "memory");
            __builtin_amdgcn_s_barrier();
            if (p + 4 < NPH) STAGE(p + 4)    // target slot = the one retired at p-1

            const int sl = p % SLOTS;
            const float* bK = &ldsK[sl * UNITF];
            const float* bV = &ldsV[sl * UNITF];
            #pragma unroll
            for (int dl = 0; dl < 4; ++dl) {
                const int d0 = q * 4 + dl;               // static weight index
                const int gc = dl * 8 + lhi * 2;
                const int o0 = (l15 * 32 + (gc ^ sw)) * 4;
                const int o1 = (l15 * 32 + ((gc + 1) ^ sw)) * 4;
                float4 ka = *(const float4*)&bK[o0];
                float4 kb = *(const float4*)&bK[o1];
                float4 va = *(const float4*)&bV[o0];
                float4 vb = *(const float4*)&bV[o1];
                kacc = __builtin_amdgcn_mfma_f32_16x16x32_bf16(
                           cvt8(ka, kb), __builtin_bit_cast(bf16x8, wk[d0]),  kacc, 0, 0, 0);
                vacc = __builtin_amdgcn_mfma_f32_16x16x32_bf16(
                           cvt8(va, vb), __builtin_bit_cast(bf16x8, wvv[d0]), vacc, 0, 0, 0);
            }
            if (q == 3) {    // end of 16-row chunk: combine K/V projections
                #pragma unroll
                for (int i = 0; i < 4; ++i)
                    sreg += (kacc[i] + bk) * (vacc[i] + bv);
                #pragma unroll
                for (int i = 0; i < 4; ++i) { kacc[i] = 0.f; vacc[i] = 0.f; }
            }
        }
    }
#undef STAGE

    // reduce over the 4 row-groups (C/D rows live in lanes ^16, ^32)
    sreg += __shfl_xor(sreg, 16);
    sreg += __shfl_xor(sreg, 32);
    if (lhi == 0) {
        int b = blockRow0 / kN;
        atomicAdd(&S[b * kBD + jrow], sreg);
    }
}

// Fused tail: 64 blocks; each block redundantly computes S->Bsum->ms->ext->LN
// for its batch b (tiny), then produces its 64-wide slice of out = normed.Wo^T + bo.
__global__ __launch_bounds__(256)
void lbm_tail(const float* __restrict__ S,    const float* __restrict__ query,
              const float* __restrict__ Wbc,  const float* __restrict__ bbc,
              const float* __restrict__ Wuq,  const float* __restrict__ buq,
              const float* __restrict__ Wue,  const float* __restrict__ bue,
              const float* __restrict__ ln_g, const float* __restrict__ ln_b,
              const float* __restrict__ Wo,   const float* __restrict__ bo,
              float* __restrict__ out)
{
    const int b = blockIdx.x >> 3;
    const int s = blockIdx.x & 7;          // 64-wide output slice
    const int t = threadIdx.x;

    __shared__ float shS[kBD];
    __shared__ float shB[kD];
    __shared__ float shMs[kBD];
    __shared__ float shN[kD];
    __shared__ float redT[4][kBD];
    __shared__ float redQ[4][kBD];
    __shared__ float redLN[8];
    __shared__ float s_mu, s_rs;

    if (t < kBD) shS[t] = S[b * kBD + t];
    __syncthreads();

    // Bsum[d] = sum_j S[j]*Wbc[d,j] + n*bbc[d]
    for (int d = t; d < kD; d += 256) {
        const float4* wr = (const float4*)(Wbc + d * kBD);
        float acc = 0.f;
        #pragma unroll
        for (int q4 = 0; q4 < 16; ++q4) {
            float4 w = wr[q4];
            acc += w.x * shS[q4*4+0] + w.y * shS[q4*4+1]
                 + w.z * shS[q4*4+2] + w.w * shS[q4*4+3];
        }
        shB[d] = acc + (float)kN * bbc[d];
    }
    __syncthreads();

    // t[jj] = Bsum.Wuq[jj,:] + n*buq ; q[jj] = query.Wuq[jj,:] + buq ; ms = q*t
    {
        const int jj = t & 63, qq = t >> 6;
        const float4* wr = (const float4*)(Wuq + jj * kD + qq * 128);
        const float4* qr = (const float4*)(query + b * kD + qq * 128);
        const float4* br = (const float4*)(shB + qq * 128);
        float at = 0.f, aq = 0.f;
        #pragma unroll
        for (int i = 0; i < 32; ++i) {
            float4 w = wr[i]; float4 bb = br[i]; float4 qv = qr[i];
            at += w.x*bb.x + w.y*bb.y + w.z*bb.z + w.w*bb.w;
            aq += w.x*qv.x + w.y*qv.y + w.z*qv.z + w.w*qv.w;
        }
        redT[qq][jj] = at; redQ[qq][jj] = aq;
    }
    __syncthreads();
    if (t < kBD) {
        float tv = redT[0][t] + redT[1][t] + redT[2][t] + redT[3][t] + (float)kN * buq[t];
        float qv = redQ[0][t] + redQ[1][t] + redQ[2][t] + redQ[3][t] + buq[t];
        shMs[t] = tv * qv;
    }
    __syncthreads();

    // ext[d] -> ret -> LN stats
    float lsum = 0.f, lsq = 0.f;
    for (int d = t; d < kD; d += 256) {
        const float4* wr = (const float4*)(Wue + d * kBD);
        float acc = 0.f;
        #pragma unroll
        for (int q4 = 0; q4 < 16; ++q4) {
            float4 w = wr[q4];
            acc += w.x * shMs[q4*4+0] + w.y * shMs[q4*4+1]
                 + w.z * shMs[q4*4+2] + w.w * shMs[q4*4+3];
        }
        float ret = (acc + (float)kN * bue[d]) * (1.0f / 64.0f);
        shN[d] = ret;
        lsum += ret; lsq += ret * ret;
    }
    #pragma unroll
    for (int m = 1; m < 64; m <<= 1) {
        lsum += __shfl_xor(lsum, m);
        lsq  += __shfl_xor(lsq, m);
    }
    if ((t & 63) == 0) { redLN[t >> 6] = lsum; redLN[4 + (t >> 6)] = lsq; }
    __syncthreads();
    if (t == 0) {
        float s0 = redLN[0] + redLN[1] + redLN[2] + redLN[3];
        float s1 = redLN[4] + redLN[5] + redLN[6] + redLN[7];
        float mu = s0 / (float)kD;
        float var = s1 / (float)kD - mu * mu;
        s_mu = mu;
        s_rs = rsqrtf(var + 1e-5f);
    }
    __syncthreads();
    {
        float mu = s_mu, rs = s_rs;
        for (int d = t; d < kD; d += 256)
            shN[d] = (shN[d] - mu) * rs * ln_g[d] + ln_b[d];
    }
    __syncthreads();

    // out slice: d = s*64 + t/4, quarter q = t&3 over the 512-dot
    {
        const int d = s * 64 + (t >> 2);
        const int q = t & 3;
        const float4* wr = (const float4*)(Wo + d * kD + q * 128);
        const float4* nr = (const float4*)(shN + q * 128);
        float acc = 0.f;
        #pragma unroll
        for (int i = 0; i < 32; ++i) {
            float4 w = wr[i]; float4 nv = nr[i];
            acc += w.x*nv.x + w.y*nv.y + w.z*nv.z + w.w*nv.w;
        }
        acc += __shfl_xor(acc, 1);
        acc += __shfl_xor(acc, 2);
        if (q == 0) out[b * kD + d] = acc + bo[d];
    }
}

extern "C" void kernel_launch(void* const* d_in, const int* in_sizes, int n_in,
                              void* d_out, int out_size, void* d_ws, size_t ws_size,
                              hipStream_t stream) {
    const float* keys   = (const float*)d_in[0];
    const float* values = (const float*)d_in[1];
    const float* query  = (const float*)d_in[2];
    const float* Wbk    = (const float*)d_in[3];
    const float* bbk    = (const float*)d_in[4];
    const float* Wbv    = (const float*)d_in[5];
    const float* bbv    = (const float*)d_in[6];
    const float* Wbc    = (const float*)d_in[7];
    const float* bbc    = (const float*)d_in[8];
    const float* Wuq    = (const float*)d_in[9];
    const float* buq    = (const float*)d_in[10];
    const float* Wue    = (const float*)d_in[11];
    const float* bue    = (const float*)d_in[12];
    const float* ln_g   = (const float*)d_in[13];
    const float* ln_b   = (const float*)d_in[14];
    const float* Wo     = (const float*)d_in[15];
    const float* bo     = (const float*)d_in[16];

    float* S   = (float*)d_ws;      // [8][64] accumulator
    float* out = (float*)d_out;

    hipMemsetAsync(S, 0, kB * kBD * sizeof(float), stream);

    const int nblocks = (kB * kN) / (ROWS * CPB);   // 512
    lbm_bind<<<dim3(nblocks), dim3(256), 0, stream>>>(keys, values, Wbk, bbk, Wbv, bbv, S);
    lbm_tail<<<dim3(kB * 8), dim3(256), 0, stream>>>(S, query, Wbc, bbc, Wuq, buq,
                                                     Wue, bue, ln_g, ln_b, Wo, bo, out);
}

// Round 5
// 60.748 us; speedup vs baseline: 1.7118x; 1.0402x over previous
//
#include <hip/hip_runtime.h>
#include <hip/hip_bf16.h>

typedef __bf16 bf16x8 __attribute__((ext_vector_type(8)));
typedef __bf16 bf16x4 __attribute__((ext_vector_type(4)));
typedef float  f32x4  __attribute__((ext_vector_type(4)));

constexpr int kD  = 512;
constexpr int kBD = 64;
constexpr int kN  = 4096;
constexpr int kB  = 8;

constexpr int BROWS = 32;   // rows per block (2 MFMA row-chunks) -> grid 1024, 4 blocks/CU
constexpr int NPH   = 8;    // phases: (chunk = p&1) x (d-unit = p>>1), unit = 16r x 128d

typedef const __attribute__((address_space(1))) void* gas_t;
typedef __attribute__((address_space(3))) void*       las_t;

static __device__ __forceinline__ void gload16(const void* g, void* l) {
    __builtin_amdgcn_global_load_lds((gas_t)g, (las_t)l, 16, 0, 0);
}

__device__ __forceinline__ bf16x8 cvt8(float4 a, float4 b) {
    bf16x8 r;
    r[0] = (__bf16)a.x; r[1] = (__bf16)a.y; r[2] = (__bf16)a.z; r[3] = (__bf16)a.w;
    r[4] = (__bf16)b.x; r[5] = (__bf16)b.y; r[6] = (__bf16)b.z; r[7] = (__bf16)b.w;
    return r;
}

// Prep: Wbk/Wbv fp32 -> bf16 in ws (L2-hot weight images for the bind kernel)
__global__ __launch_bounds__(256)
void lbm_prep(const float* __restrict__ Wbk, const float* __restrict__ Wbv,
              __bf16* __restrict__ wsk, __bf16* __restrict__ wsv)
{
    int i = (blockIdx.x * 256 + threadIdx.x) * 4;   // grid 32 -> 32768 elems
    float4 a = *(const float4*)(Wbk + i);
    float4 b = *(const float4*)(Wbv + i);
    bf16x4 ka, vb;
    ka[0] = (__bf16)a.x; ka[1] = (__bf16)a.y; ka[2] = (__bf16)a.z; ka[3] = (__bf16)a.w;
    vb[0] = (__bf16)b.x; vb[1] = (__bf16)b.y; vb[2] = (__bf16)b.z; vb[3] = (__bf16)b.w;
    *(bf16x4*)(wsk + i) = ka;
    *(bf16x4*)(wsv + i) = vb;
}

// S[b,j] = sum_n (keys[b,n,:].Wbk[j,:] + bbk[j]) * (values[b,n,:].Wbv[j,:] + bbv[j])
//
// m97-style: 32 KB double-buffered LDS (16r x 128d x {K,V}), global_load_lds
// staging with XOR-pre-swizzled source granules, plain __syncthreads dbuf.
// 4 blocks/CU x 4 waves = 16 waves/CU -- TLP is the latency-hiding engine.
// B-fragments (weights) stream from the bf16 ws image (L2-hot), loaded per
// even phase and reused for the odd phase's row-chunk.
__global__ __launch_bounds__(256, 4)
void lbm_bind(const float* __restrict__ keys, const float* __restrict__ values,
              const __bf16* __restrict__ wsk, const __bf16* __restrict__ wsv,
              const float* __restrict__ bbk,  const float* __restrict__ bbv,
              float* __restrict__ S)
{
    __shared__ float lds[2][2][16 * 128];   // [buf][K/V][16 rows x 128 d] = 32 KB

    const int tid = threadIdx.x;
    const int wv  = tid >> 6;
    const int ln  = tid & 63;
    const int l15 = ln & 15;
    const int lhi = ln >> 4;
    const int sw  = l15 & 7;             // row XOR swizzle key
    const int jrow = wv * 16 + l15;      // weight row (j) for B-operand
    const int dk   = lhi * 8;

    const int blockRow0 = blockIdx.x * BROWS;

    // STAGE phase p into buf (p&1): chunk (p&1), d-unit (p>>1). 4 gload16/thread.
#define STAGE(p)                                                              \
    {                                                                         \
        _Pragma("unroll")                                                     \
        for (int i_ = 0; i_ < 2; ++i_) {                                      \
            int g_  = i_ * 256 + tid;      /* granule 0..511 */               \
            int r_  = g_ >> 5;             /* row 0..15 */                    \
            int gl_ = g_ & 31;             /* granule in row-unit */          \
            int gs_ = gl_ ^ (r_ & 7);      /* swizzled source granule */      \
            size_t so_ = (size_t)(blockRow0 + ((p) & 1) * 16 + r_) * kD       \
                         + ((p) >> 1) * 128 + gs_ * 4;                        \
            gload16(keys   + so_, &lds[(p) & 1][0][g_ * 4]);                  \
            gload16(values + so_, &lds[(p) & 1][1][g_ * 4]);                  \
        }                                                                     \
    }

    STAGE(0)
    const float bk = bbk[jrow];
    const float bv = bbv[jrow];
    __syncthreads();   // phase-0 data resident

    f32x4 kacc[2] = {{0.f,0.f,0.f,0.f},{0.f,0.f,0.f,0.f}};
    f32x4 vacc[2] = {{0.f,0.f,0.f,0.f},{0.f,0.f,0.f,0.f}};
    bf16x8 wkf[4], wvf[4];   // current d-unit's weight fragments (reused even->odd)

    #pragma unroll
    for (int p = 0; p < NPH; ++p) {
        if (p + 1 < NPH) STAGE(p + 1)     // next unit in flight under this compute

        const int bf = p & 1;             // buffer == chunk parity (compile-time)
        const float* bK = &lds[bf][0][0];
        const float* bV = &lds[bf][1][0];

        #pragma unroll
        for (int dl = 0; dl < 4; ++dl) {
            const int d0 = (p >> 1) * 4 + dl;            // global d-step
            if (bf == 0) {                                // load weights once per d-unit
                wkf[dl] = *(const bf16x8*)(wsk + jrow * kD + d0 * 32 + dk);
                wvf[dl] = *(const bf16x8*)(wsv + jrow * kD + d0 * 32 + dk);
            }
            const int gc = dl * 8 + lhi * 2;
            const int o0 = (l15 * 32 + (gc ^ sw)) * 4;
            const int o1 = (l15 * 32 + ((gc + 1) ^ sw)) * 4;
            float4 ka = *(const float4*)&bK[o0];
            float4 kb = *(const float4*)&bK[o1];
            float4 va = *(const float4*)&bV[o0];
            float4 vb = *(const float4*)&bV[o1];
            kacc[bf] = __builtin_amdgcn_mfma_f32_16x16x32_bf16(cvt8(ka, kb), wkf[dl], kacc[bf], 0, 0, 0);
            vacc[bf] = __builtin_amdgcn_mfma_f32_16x16x32_bf16(cvt8(va, vb), wvf[dl], vacc[bf], 0, 0, 0);
        }
        __syncthreads();   // drains staging of p+1; protects buf reuse
    }
#undef STAGE

    // combine projections: sreg = sum over this block's 32 rows of (k+bk)*(v+bv)
    float sreg = 0.0f;
    #pragma unroll
    for (int c = 0; c < 2; ++c)
        #pragma unroll
        for (int i = 0; i < 4; ++i)
            sreg += (kacc[c][i] + bk) * (vacc[c][i] + bv);

    // reduce over the 4 row-groups (C/D rows live in lanes ^16, ^32)
    sreg += __shfl_xor(sreg, 16);
    sreg += __shfl_xor(sreg, 32);
    if (lhi == 0) {
        int b = blockRow0 / kN;
        atomicAdd(&S[b * kBD + jrow], sreg);
    }
}

// Fused tail: 64 blocks; each block redundantly computes S->Bsum->ms->ext->LN
// for its batch b (tiny), then produces its 64-wide slice of out = normed.Wo^T + bo.
__global__ __launch_bounds__(256)
void lbm_tail(const float* __restrict__ S,    const float* __restrict__ query,
              const float* __restrict__ Wbc,  const float* __restrict__ bbc,
              const float* __restrict__ Wuq,  const float* __restrict__ buq,
              const float* __restrict__ Wue,  const float* __restrict__ bue,
              const float* __restrict__ ln_g, const float* __restrict__ ln_b,
              const float* __restrict__ Wo,   const float* __restrict__ bo,
              float* __restrict__ out)
{
    const int b = blockIdx.x >> 3;
    const int s = blockIdx.x & 7;          // 64-wide output slice
    const int t = threadIdx.x;

    __shared__ float shS[kBD];
    __shared__ float shB[kD];
    __shared__ float shMs[kBD];
    __shared__ float shN[kD];
    __shared__ float redT[4][kBD];
    __shared__ float redQ[4][kBD];
    __shared__ float redLN[8];
    __shared__ float s_mu, s_rs;

    if (t < kBD) shS[t] = S[b * kBD + t];
    __syncthreads();

    // Bsum[d] = sum_j S[j]*Wbc[d,j] + n*bbc[d]
    for (int d = t; d < kD; d += 256) {
        const float4* wr = (const float4*)(Wbc + d * kBD);
        float acc = 0.f;
        #pragma unroll
        for (int q4 = 0; q4 < 16; ++q4) {
            float4 w = wr[q4];
            acc += w.x * shS[q4*4+0] + w.y * shS[q4*4+1]
                 + w.z * shS[q4*4+2] + w.w * shS[q4*4+3];
        }
        shB[d] = acc + (float)kN * bbc[d];
    }
    __syncthreads();

    // t[jj] = Bsum.Wuq[jj,:] + n*buq ; q[jj] = query.Wuq[jj,:] + buq ; ms = q*t
    {
        const int jj = t & 63, qq = t >> 6;
        const float4* wr = (const float4*)(Wuq + jj * kD + qq * 128);
        const float4* qr = (const float4*)(query + b * kD + qq * 128);
        const float4* br = (const float4*)(shB + qq * 128);
        float at = 0.f, aq = 0.f;
        #pragma unroll
        for (int i = 0; i < 32; ++i) {
            float4 w = wr[i]; float4 bb = br[i]; float4 qv = qr[i];
            at += w.x*bb.x + w.y*bb.y + w.z*bb.z + w.w*bb.w;
            aq += w.x*qv.x + w.y*qv.y + w.z*qv.z + w.w*qv.w;
        }
        redT[qq][jj] = at; redQ[qq][jj] = aq;
    }
    __syncthreads();
    if (t < kBD) {
        float tv = redT[0][t] + redT[1][t] + redT[2][t] + redT[3][t] + (float)kN * buq[t];
        float qv = redQ[0][t] + redQ[1][t] + redQ[2][t] + redQ[3][t] + buq[t];
        shMs[t] = tv * qv;
    }
    __syncthreads();

    // ext[d] -> ret -> LN stats
    float lsum = 0.f, lsq = 0.f;
    for (int d = t; d < kD; d += 256) {
        const float4* wr = (const float4*)(Wue + d * kBD);
        float acc = 0.f;
        #pragma unroll
        for (int q4 = 0; q4 < 16; ++q4) {
            float4 w = wr[q4];
            acc += w.x * shMs[q4*4+0] + w.y * shMs[q4*4+1]
                 + w.z * shMs[q4*4+2] + w.w * shMs[q4*4+3];
        }
        float ret = (acc + (float)kN * bue[d]) * (1.0f / 64.0f);
        shN[d] = ret;
        lsum += ret; lsq += ret * ret;
    }
    #pragma unroll
    for (int m = 1; m < 64; m <<= 1) {
        lsum += __shfl_xor(lsum, m);
        lsq  += __shfl_xor(lsq, m);
    }
    if ((t & 63) == 0) { redLN[t >> 6] = lsum; redLN[4 + (t >> 6)] = lsq; }
    __syncthreads();
    if (t == 0) {
        float s0 = redLN[0] + redLN[1] + redLN[2] + redLN[3];
        float s1 = redLN[4] + redLN[5] + redLN[6] + redLN[7];
        float mu = s0 / (float)kD;
        float var = s1 / (float)kD - mu * mu;
        s_mu = mu;
        s_rs = rsqrtf(var + 1e-5f);
    }
    __syncthreads();
    {
        float mu = s_mu, rs = s_rs;
        for (int d = t; d < kD; d += 256)
            shN[d] = (shN[d] - mu) * rs * ln_g[d] + ln_b[d];
    }
    __syncthreads();

    // out slice: d = s*64 + t/4, quarter q = t&3 over the 512-dot
    {
        const int d = s * 64 + (t >> 2);
        const int q = t & 3;
        const float4* wr = (const float4*)(Wo + d * kD + q * 128);
        const float4* nr = (const float4*)(shN + q * 128);
        float acc = 0.f;
        #pragma unroll
        for (int i = 0; i < 32; ++i) {
            float4 w = wr[i]; float4 nv = nr[i];
            acc += w.x*nv.x + w.y*nv.y + w.z*nv.z + w.w*nv.w;
        }
        acc += __shfl_xor(acc, 1);
        acc += __shfl_xor(acc, 2);
        if (q == 0) out[b * kD + d] = acc + bo[d];
    }
}

extern "C" void kernel_launch(void* const* d_in, const int* in_sizes, int n_in,
                              void* d_out, int out_size, void* d_ws, size_t ws_size,
                              hipStream_t stream) {
    const float* keys   = (const float*)d_in[0];
    const float* values = (const float*)d_in[1];
    const float* query  = (const float*)d_in[2];
    const float* Wbk    = (const float*)d_in[3];
    const float* bbk    = (const float*)d_in[4];
    const float* Wbv    = (const float*)d_in[5];
    const float* bbv    = (const float*)d_in[6];
    const float* Wbc    = (const float*)d_in[7];
    const float* bbc    = (const float*)d_in[8];
    const float* Wuq    = (const float*)d_in[9];
    const float* buq    = (const float*)d_in[10];
    const float* Wue    = (const float*)d_in[11];
    const float* bue    = (const float*)d_in[12];
    const float* ln_g   = (const float*)d_in[13];
    const float* ln_b   = (const float*)d_in[14];
    const float* Wo     = (const float*)d_in[15];
    const float* bo     = (const float*)d_in[16];

    // ws layout: S[8][64] f32 (2 KB), wsk[64*512] bf16 (64 KB), wsv[64*512] bf16 (64 KB)
    float*  Sacc = (float*)d_ws;
    __bf16* wsk  = (__bf16*)((char*)d_ws + 2048);
    __bf16* wsv  = wsk + kBD * kD;
    float*  out  = (float*)d_out;

    hipMemsetAsync(Sacc, 0, kB * kBD * sizeof(float), stream);

    lbm_prep<<<dim3(32), dim3(256), 0, stream>>>(Wbk, Wbv, wsk, wsv);

    const int nblocks = (kB * kN) / BROWS;   // 1024 -> 4 blocks/CU
    lbm_bind<<<dim3(nblocks), dim3(256), 0, stream>>>(keys, values, wsk, wsv, bbk, bbv, Sacc);
    lbm_tail<<<dim3(kB * 8), dim3(256), 0, stream>>>(Sacc, query, Wbc, bbc, Wuq, buq,
                                                     Wue, bue, ln_g, ln_b, Wo, bo, out);
}